// Round 1
// baseline (902.848 us; speedup 1.0000x reference)
//
#include <hip/hip_runtime.h>
#include <math.h>

#define B_    32
#define CIN   256
#define HID   256
#define OC    65
#define A_    9
#define H_    56
#define W_    56
#define HW    3136
#define AHW   28224      // A_*HW
#define NBOX  64
#define M_    2048
#define CNUM  20
#define TP    64         // pixel tile
#define KC    32         // c-chunk
#define WPAD  260        // padded row for transposed w1 chunk (avoids bank conflicts, keeps 16B align)
#define NTILE 49         // HW / TP

// d_out layout: [0] total_loss | [1 .. 1+IOU_N) iou_mat | [1+IOU_N ..) class_pos
#define IOU_N ((size_t)B_ * AHW * NBOX)   // 57,802,752

__device__ __forceinline__ void fma4(float4& a, float wc, const float4& f) {
    a.x += wc * f.x; a.y += wc * f.y; a.z += wc * f.z; a.w += wc * f.w;
}

// Fused conv1(256->256, leaky 0.01) + conv2(256->65). One block = one batch b, 64-pixel tile.
// LDS (64 KB, aliased by phase):
//   phase1: wt_s[KC][WPAD] (w1 chunk, transposed)  + feat_s[KC][TP]
//   phase3: hid_s[HID][TP]
__global__ __launch_bounds__(256) void conv_fused_kernel(
    const float* __restrict__ features, const float* __restrict__ w1,
    const float* __restrict__ b1, const float* __restrict__ w2,
    const float* __restrict__ b2, float* __restrict__ x2)
{
    __shared__ float lds[HID * TP];          // 16384 floats = 64 KB
    float* wt_s   = lds;                     // KC*WPAD = 8320 floats
    float* feat_s = lds + KC * WPAD;         // 2048 floats (ends at 10368)
    float* hid_s  = lds;                     // aliased after phase 1

    const int t   = threadIdx.x;
    const int bid = blockIdx.x;
    const int b   = bid / NTILE;
    const int p0  = (bid - b * NTILE) * TP;
    const float* fbase = features + (size_t)b * CIN * HW + p0;

    const int og = t >> 2;   // 0..63  -> o = og*4 + i
    const int po = t & 3;    // 0..3   -> p = po*16 + jj*4 + j

    float4 acc[4][4];
#pragma unroll
    for (int i = 0; i < 4; ++i)
#pragma unroll
        for (int j = 0; j < 4; ++j) acc[i][j] = make_float4(0.f, 0.f, 0.f, 0.f);

    for (int c0 = 0; c0 < CIN; c0 += KC) {
        __syncthreads();
        // stage w1 chunk transposed: wt_s[cc][o] = w1[o][c0+cc]
#pragma unroll
        for (int it = 0; it < 8; ++it) {
            const int o   = (t >> 3) + (it << 5);
            const int cc4 = (t & 7) << 2;
            const float4 wv = *(const float4*)(w1 + (size_t)o * CIN + c0 + cc4);
            wt_s[(cc4 + 0) * WPAD + o] = wv.x;
            wt_s[(cc4 + 1) * WPAD + o] = wv.y;
            wt_s[(cc4 + 2) * WPAD + o] = wv.z;
            wt_s[(cc4 + 3) * WPAD + o] = wv.w;
        }
        // stage feature chunk: feat_s[cc][p] = features[b][c0+cc][p0+p]
#pragma unroll
        for (int it = 0; it < 2; ++it) {
            const int idx = t + (it << 8);      // float4 index 0..511
            const int p4  = idx & 15;
            const int cc  = idx >> 4;
            const float4 fv = *(const float4*)(fbase + (size_t)(c0 + cc) * HW + (p4 << 2));
            *(float4*)(feat_s + cc * TP + (p4 << 2)) = fv;
        }
        __syncthreads();

#pragma unroll
        for (int cc = 0; cc < KC; ++cc) {
            const float4 wv = *(const float4*)(wt_s + cc * WPAD + (og << 2));
            const float* fr = feat_s + cc * TP + (po << 4);
            const float4 f0 = *(const float4*)(fr + 0);
            const float4 f1 = *(const float4*)(fr + 4);
            const float4 f2 = *(const float4*)(fr + 8);
            const float4 f3 = *(const float4*)(fr + 12);
            const float ws0 = wv.x, ws1 = wv.y, ws2 = wv.z, ws3 = wv.w;
            fma4(acc[0][0], ws0, f0); fma4(acc[0][1], ws0, f1); fma4(acc[0][2], ws0, f2); fma4(acc[0][3], ws0, f3);
            fma4(acc[1][0], ws1, f0); fma4(acc[1][1], ws1, f1); fma4(acc[1][2], ws1, f2); fma4(acc[1][3], ws1, f3);
            fma4(acc[2][0], ws2, f0); fma4(acc[2][1], ws2, f1); fma4(acc[2][2], ws2, f2); fma4(acc[2][3], ws2, f3);
            fma4(acc[3][0], ws3, f0); fma4(acc[3][1], ws3, f1); fma4(acc[3][2], ws3, f2); fma4(acc[3][3], ws3, f3);
        }
    }
    __syncthreads();   // all wt_s/feat_s reads done; safe to alias as hid_s

    // bias + leaky relu, write hidden to LDS
#pragma unroll
    for (int i = 0; i < 4; ++i) {
        const int o = (og << 2) + i;
        const float bia = b1[o];
#pragma unroll
        for (int jj = 0; jj < 4; ++jj) {
            float4 v = acc[i][jj];
            v.x += bia; v.y += bia; v.z += bia; v.w += bia;
            v.x = v.x < 0.f ? 0.01f * v.x : v.x;
            v.y = v.y < 0.f ? 0.01f * v.y : v.y;
            v.z = v.z < 0.f ? 0.01f * v.z : v.z;
            v.w = v.w < 0.f ? 0.01f * v.w : v.w;
            *(float4*)(hid_s + (size_t)o * TP + (po << 4) + (jj << 2)) = v;
        }
    }
    __syncthreads();

    // phase 3: conv2 (65 outputs). thread t: p = t&63, ob = t>>6; o2 = q*16 + ob*4 + i
    const int p  = t & 63;
    const int ob = t >> 6;
    float* xout = x2 + (size_t)b * OC * HW + p0 + p;

#pragma unroll 1
    for (int q = 0; q < 4; ++q) {
        const int o2b = (q << 4) + (ob << 2);
        float s0 = 0.f, s1 = 0.f, s2 = 0.f, s3 = 0.f;
        const float* w2r0 = w2 + (size_t)(o2b + 0) * HID;
        const float* w2r1 = w2 + (size_t)(o2b + 1) * HID;
        const float* w2r2 = w2 + (size_t)(o2b + 2) * HID;
        const float* w2r3 = w2 + (size_t)(o2b + 3) * HID;
#pragma unroll 4
        for (int c = 0; c < HID; c += 4) {
            const float h0 = hid_s[(c + 0) * TP + p];
            const float h1 = hid_s[(c + 1) * TP + p];
            const float h2 = hid_s[(c + 2) * TP + p];
            const float h3 = hid_s[(c + 3) * TP + p];
            const float4 w0 = *(const float4*)(w2r0 + c);
            const float4 w1v = *(const float4*)(w2r1 + c);
            const float4 w2v = *(const float4*)(w2r2 + c);
            const float4 w3 = *(const float4*)(w2r3 + c);
            s0 += w0.x * h0 + w0.y * h1 + w0.z * h2 + w0.w * h3;
            s1 += w1v.x * h0 + w1v.y * h1 + w1v.z * h2 + w1v.w * h3;
            s2 += w2v.x * h0 + w2v.y * h1 + w2v.z * h2 + w2v.w * h3;
            s3 += w3.x * h0 + w3.y * h1 + w3.z * h2 + w3.w * h3;
        }
        xout[(size_t)(o2b + 0) * HW] = s0 + b2[o2b + 0];
        xout[(size_t)(o2b + 1) * HW] = s1 + b2[o2b + 1];
        xout[(size_t)(o2b + 2) * HW] = s2 + b2[o2b + 2];
        xout[(size_t)(o2b + 3) * HW] = s3 + b2[o2b + 3];
    }
    // tail channel o2 = 64, handled by wave 0
    if (ob == 0) {
        float s = 0.f;
        const float* w2r = w2 + (size_t)64 * HID;
#pragma unroll 4
        for (int c = 0; c < HID; c += 4) {
            const float4 wv = *(const float4*)(w2r + c);
            s += wv.x * hid_s[(c + 0) * TP + p] + wv.y * hid_s[(c + 1) * TP + p]
               + wv.z * hid_s[(c + 2) * TP + p] + wv.w * hid_s[(c + 3) * TP + p];
        }
        xout[(size_t)64 * HW] = s + b2[64];
    }
}

// One wave per proposal (b,a,h,w); lane = gt box index. Coalesced 256B stores per wave.
__global__ __launch_bounds__(256) void iou_kernel(
    const float* __restrict__ x2, const float* __restrict__ anc,
    const float* __restrict__ grid, const float* __restrict__ bboxes,
    float* __restrict__ iou_out)
{
    const int t    = threadIdx.x;
    const int lane = t & 63;
    const int widx = blockIdx.x * 4 + (t >> 6);
    const int b  = widx / AHW;
    const int r  = widx - b * AHW;
    const int a  = r / HW;
    const int hw = r - a * HW;
    const int h  = hw / W_;
    const int w  = hw - h * W_;

    const float* xb = x2 + ((size_t)b * OC + 5 * a) * HW + hw;
    const float tx = xb[1 * HW], ty = xb[2 * HW], tw = xb[3 * HW], th = xb[4 * HW];
    const size_t gidx = (((size_t)b * H_ + h) * W_ + w) * 2;
    const float gx = grid[gidx], gy = grid[gidx + 1];
    const float aw = anc[2 * a], ah = anc[2 * a + 1];

    const float nw = aw * expf(tw);
    const float nh = ah * expf(th);
    const float cx = gx + tx, cy = gy + ty;
    const float px1 = cx - 0.5f * nw, px2 = cx + 0.5f * nw;
    const float py1 = cy - 0.5f * nh, py2 = cy + 0.5f * nh;
    const float parea = nw * nh;

    const float* gb = bboxes + ((size_t)b * NBOX + lane) * 5;
    const float bx1 = gb[0], by1 = gb[1], bx2 = gb[2], by2 = gb[3];
    const float garea = (bx2 - bx1) * (by2 - by1);

    const float iw = fminf(px2, bx2) - fmaxf(px1, bx1);
    const float ih = fminf(py2, by2) - fmaxf(py1, by1);
    const float inter = fmaxf(iw, 0.f) * fmaxf(ih, 0.f);
    iou_out[(size_t)widx * NBOX + lane] = inter / (garea + parea - inter);
}

// class_pos[m][c] = x2[bi, 45+c, hi, wi]
__global__ __launch_bounds__(256) void class_kernel(
    const float* __restrict__ x2, const int* __restrict__ pos_idx,
    float* __restrict__ cls_out)
{
    const int g = blockIdx.x * 256 + threadIdx.x;   // 0 .. 40959
    const int m = g / CNUM;
    const int c = g - m * CNUM;
    const int idx = pos_idx[m];
    const int b  = idx / AHW;
    const int hw = idx % HW;
    cls_out[g] = x2[((size_t)b * OC + 45 + c) * HW + hw];
}

// total_loss = conf_loss + reg_loss, single block
__global__ __launch_bounds__(256) void loss_kernel(
    const float* __restrict__ x2, const float* __restrict__ gt_off,
    const int* __restrict__ pos_idx, const int* __restrict__ neg_idx,
    float* __restrict__ out0)
{
    const int t = threadIdx.x;
    float csum = 0.f, rsum = 0.f;
    for (int m = t; m < M_; m += 256) {
        const int idx = pos_idx[m];
        const int b  = idx / AHW;
        const int r  = idx - b * AHW;
        const int a  = r / HW;
        const int hw = r - a * HW;
        const float* xb = x2 + ((size_t)b * OC + 5 * a) * HW + hw;
        const float s = 1.f / (1.f + expf(-xb[0]));
        csum += (s - 1.f) * (s - 1.f);
#pragma unroll
        for (int k = 0; k < 4; ++k) {
            const float d = xb[(size_t)(k + 1) * HW] - gt_off[m * 4 + k];
            rsum += d * d;
        }
    }
    for (int m = t; m < M_; m += 256) {
        const int idx = neg_idx[m];
        const int b  = idx / AHW;
        const int r  = idx - b * AHW;
        const int a  = r / HW;
        const int hw = r - a * HW;
        const float s = 1.f / (1.f + expf(-x2[((size_t)b * OC + 5 * a) * HW + hw]));
        csum += s * s;
    }
    __shared__ float red[8];
#pragma unroll
    for (int off = 32; off > 0; off >>= 1) {
        csum += __shfl_down(csum, off, 64);
        rsum += __shfl_down(rsum, off, 64);
    }
    if ((t & 63) == 0) { red[t >> 6] = csum; red[4 + (t >> 6)] = rsum; }
    __syncthreads();
    if (t == 0) {
        const float c = red[0] + red[1] + red[2] + red[3];
        const float r = red[4] + red[5] + red[6] + red[7];
        out0[0] = c / (2.f * (float)M_) + r / (float)M_;
    }
}

extern "C" void kernel_launch(void* const* d_in, const int* in_sizes, int n_in,
                              void* d_out, int out_size, void* d_ws, size_t ws_size,
                              hipStream_t stream) {
    (void)in_sizes; (void)n_in; (void)out_size; (void)ws_size;
    const float* features = (const float*)d_in[0];
    const float* w1       = (const float*)d_in[1];
    const float* b1       = (const float*)d_in[2];
    const float* w2       = (const float*)d_in[3];
    const float* b2       = (const float*)d_in[4];
    const float* anc      = (const float*)d_in[5];
    const float* grid     = (const float*)d_in[6];
    const float* bboxes   = (const float*)d_in[7];
    const float* gt_off   = (const float*)d_in[8];
    const int*   pos_idx  = (const int*)d_in[9];
    const int*   neg_idx  = (const int*)d_in[10];
    float* out = (float*)d_out;
    float* x2  = (float*)d_ws;   // B*OC*HW fp32 = 26 MB scratch

    conv_fused_kernel<<<B_ * NTILE, 256, 0, stream>>>(features, w1, b1, w2, b2, x2);
    iou_kernel<<<(B_ * AHW) / 4, 256, 0, stream>>>(x2, anc, grid, bboxes, out + 1);
    class_kernel<<<(M_ * CNUM) / 256, 256, 0, stream>>>(x2, pos_idx, out + 1 + IOU_N);
    loss_kernel<<<1, 256, 0, stream>>>(x2, gt_off, pos_idx, neg_idx, out);
}

// Round 3
// 653.589 us; speedup vs baseline: 1.3814x; 1.3814x over previous
//
#include <hip/hip_runtime.h>
#include <math.h>

#define B_    32
#define CIN   256
#define HID   256
#define OC    65
#define A_    9
#define H_    56
#define W_    56
#define HW    3136
#define AHW   28224
#define NBOX  64
#define M_    2048
#define CNUM  20
#define NTILE 49         // HW / 64

#define IOU_N ((size_t)B_ * AHW * NBOX)   // 57,802,752
#define X2_BYTES ((size_t)B_ * OC * HW * 4)  // 26,091,520

typedef _Float16 half8 __attribute__((ext_vector_type(8)));
typedef float f32x16 __attribute__((ext_vector_type(16)));
typedef float f32x4  __attribute__((ext_vector_type(4)));

__device__ __forceinline__ unsigned int pkh(float a, float b) {
    _Float16 ha = (_Float16)a, hb = (_Float16)b;
    unsigned short ua = __builtin_bit_cast(unsigned short, ha);
    unsigned short ub = __builtin_bit_cast(unsigned short, hb);
    return (unsigned int)ua | ((unsigned int)ub << 16);
}

// Convert weights to fp16 once per launch (w1: 65536 el, w2: 16640 el).
__global__ __launch_bounds__(256) void prep_kernel(
    const float* __restrict__ w1, const float* __restrict__ w2,
    _Float16* __restrict__ w1h, _Float16* __restrict__ w2h)
{
    const int i = blockIdx.x * 256 + threadIdx.x;
    if (i < 65536) w1h[i] = (_Float16)w1[i];
    if (i < 16640) w2h[i] = (_Float16)w2[i];
}

// Fused conv1(256->256, leaky) + conv2(256->65) via fp16 MFMA, fp32 accumulate.
// Block = (batch b, 64-pixel tile). 4 waves.
// Phase1: wave w computes hidden rows [64w,64w+64) x 64 px with 2x2 32x32x16 accums.
//   A (w1h) fragments loaded straight from global (16B/lane, L2-hot).
//   B (features) staged to LDS in fragment order, fp32->fp16 during staging.
// Phase2: bias+leaky, repack into conv2 B-fragment order (16x16x32) in LDS.
// Phase3: conv2 rows padded to 80 (5 tiles of 16), A from global w2h, store x2 fp32.
__global__ __launch_bounds__(256) void conv_fused_kernel(
    const float* __restrict__ features, const _Float16* __restrict__ w1h,
    const float* __restrict__ b1, const _Float16* __restrict__ w2h,
    const float* __restrict__ b2, float* __restrict__ x2)
{
    __shared__ _Float16 fB[2 * 2 * 64 * 8];     // 4 KB  feat fragments (2 ks x 2 pt)
    __shared__ _Float16 hidf[8 * 4 * 64 * 8];   // 32 KB hidden fragments (8 ks2 x 4 pt2)
    __shared__ float bias_s[HID];               // 1 KB

    const int t    = threadIdx.x;
    const int lane = t & 63;
    const int w    = t >> 6;
    const int bid  = blockIdx.x;
    const int b    = bid / NTILE;
    const int p0   = (bid - b * NTILE) * 64;
    const float* fbase = features + (size_t)b * CIN * HW + p0;

    bias_s[t] = b1[t];

    f32x16 facc[2][2];
#pragma unroll
    for (int ot = 0; ot < 2; ++ot)
#pragma unroll
        for (int pt = 0; pt < 2; ++pt)
#pragma unroll
            for (int e = 0; e < 16; ++e) facc[ot][pt][e] = 0.f;

    // staging coords (constant per thread)
    const int pstage = (t & 15) * 4;        // pixel base (4 px per thread)
    const int kk     = (t >> 4) * 2;        // row pair within 32-k chunk
    const int ksS    = kk >> 4;
    const int gS     = (kk >> 3) & 1;
    const int j0     = kk & 7;              // even
    const int m31    = lane & 31;
    const int ghalf  = lane >> 5;

    for (int k0 = 0; k0 < CIN; k0 += 32) {
        // ---- stage feature chunk [32 k][64 p] -> fp16 fragment order ----
        const float4 r0 = *(const float4*)(fbase + (size_t)(k0 + kk) * HW + pstage);
        const float4 r1 = *(const float4*)(fbase + (size_t)(k0 + kk + 1) * HW + pstage);
        const float a0[4] = {r0.x, r0.y, r0.z, r0.w};
        const float a1[4] = {r1.x, r1.y, r1.z, r1.w};
#pragma unroll
        for (int e = 0; e < 4; ++e) {
            const int p     = pstage + e;
            const int lane2 = gS * 32 + (p & 31);
            const int pt    = p >> 5;
            const int frag  = (ksS * 2 + pt) * 64 + lane2;
            *(unsigned int*)&fB[frag * 8 + j0] = pkh(a0[e], a1[e]);
        }
        __syncthreads();

        // ---- compute: 2 K-steps of 16 ----
#pragma unroll
        for (int ks = 0; ks < 2; ++ks) {
            half8 af[2];
#pragma unroll
            for (int ot = 0; ot < 2; ++ot) {
                const int o  = w * 64 + ot * 32 + m31;
                const int kA = k0 + ks * 16 + ghalf * 8;
                af[ot] = *(const half8*)(w1h + (size_t)o * CIN + kA);
            }
#pragma unroll
            for (int pt = 0; pt < 2; ++pt) {
                const half8 bf = *(const half8*)&fB[((ks * 2 + pt) * 64 + lane) * 8];
                facc[0][pt] = __builtin_amdgcn_mfma_f32_32x32x16_f16(af[0], bf, facc[0][pt], 0, 0, 0);
                facc[1][pt] = __builtin_amdgcn_mfma_f32_32x32x16_f16(af[1], bf, facc[1][pt], 0, 0, 0);
            }
        }
        __syncthreads();
    }

    // ---- phase 2: bias + leaky relu, repack to conv2 B-fragment order ----
    const int col = lane & 31;
#pragma unroll
    for (int ot = 0; ot < 2; ++ot) {
        const int ks2 = w * 2 + ot;
#pragma unroll
        for (int pt = 0; pt < 2; ++pt) {
            const int pt2 = pt * 2 + (col >> 4);
            const int n15 = col & 15;
#pragma unroll
            for (int q = 0; q < 4; ++q) {
                float hv[4];
#pragma unroll
                for (int i = 0; i < 4; ++i) {
                    const int row = i + 8 * q + 4 * ghalf;
                    float v = facc[ot][pt][q * 4 + i] + bias_s[w * 64 + ot * 32 + row];
                    hv[i] = v < 0.f ? 0.01f * v : v;
                }
                const int frag = (ks2 * 4 + pt2) * 64 + (q * 16 + n15);
                *(unsigned int*)&hidf[frag * 8 + 4 * ghalf]     = pkh(hv[0], hv[1]);
                *(unsigned int*)&hidf[frag * 8 + 4 * ghalf + 2] = pkh(hv[2], hv[3]);
            }
        }
    }
    __syncthreads();

    // ---- phase 3: conv2 via 16x16x32 MFMA. wave w owns pixels [16w,16w+16). ----
    f32x4 c2[5];
#pragma unroll
    for (int rt = 0; rt < 5; ++rt)
#pragma unroll
        for (int e = 0; e < 4; ++e) c2[rt][e] = 0.f;

    const int m16 = lane & 15;
    const int kgr = lane >> 4;
#pragma unroll 2
    for (int ks2 = 0; ks2 < 8; ++ks2) {
        const half8 bf = *(const half8*)&hidf[((ks2 * 4 + w) * 64 + lane) * 8];
#pragma unroll
        for (int rt = 0; rt < 5; ++rt) {
            const int o2 = rt * 16 + m16;
            half8 af;
            if (o2 < OC) {
                const int kA = ks2 * 32 + kgr * 8;
                af = *(const half8*)(w2h + (size_t)o2 * HID + kA);
            } else {
#pragma unroll
                for (int e = 0; e < 8; ++e) af[e] = (_Float16)0.f;
            }
            c2[rt] = __builtin_amdgcn_mfma_f32_16x16x32_f16(af, bf, c2[rt], 0, 0, 0);
        }
    }

    float* xb = x2 + (size_t)b * OC * HW + p0 + w * 16 + m16;
#pragma unroll
    for (int rt = 0; rt < 5; ++rt) {
#pragma unroll
        for (int r = 0; r < 4; ++r) {
            const int o2 = rt * 16 + kgr * 4 + r;
            if (o2 < OC) xb[(size_t)o2 * HW] = c2[rt][r] + b2[o2];
        }
    }
}

// Block = 64 proposals (one (b,a), consecutive hw) x 64 boxes.
// Threads 0..63 build proposals into LDS; 64..127 load boxes.
// Each thread computes 16 ious -> 4 contiguous float4 nontemporal stores.
__global__ __launch_bounds__(256) void iou_kernel(
    const float* __restrict__ x2, const float* __restrict__ anc,
    const float* __restrict__ grid, const float* __restrict__ bboxes,
    float* __restrict__ iou_out)
{
    __shared__ float prx1[64], pry1[64], prx2[64], pry2[64];
    __shared__ float parea[64];
    __shared__ float bx1[64], by1[64], bx2s[64], by2s[64], bga[64];

    const int t    = threadIdx.x;
    const int blk  = blockIdx.x;
    const int b    = blk / (A_ * NTILE);
    const int r    = blk - b * (A_ * NTILE);
    const int a    = r / NTILE;
    const int tile = r - a * NTILE;
    const int hw0  = tile * 64;

    if (t < 64) {
        const int hw = hw0 + t;
        const int h  = hw / W_;
        const int wv = hw - h * W_;
        const float* xb = x2 + ((size_t)b * OC + 5 * a) * HW + hw;
        const float tx = xb[HW], ty = xb[2 * HW], tw = xb[3 * HW], th = xb[4 * HW];
        const size_t gi = (((size_t)b * H_ + h) * W_ + wv) * 2;
        const float gx = grid[gi], gy = grid[gi + 1];
        const float nw = anc[2 * a]     * __expf(tw);
        const float nh = anc[2 * a + 1] * __expf(th);
        const float cx = gx + tx, cy = gy + ty;
        prx1[t] = cx - 0.5f * nw; pry1[t] = cy - 0.5f * nh;
        prx2[t] = cx + 0.5f * nw; pry2[t] = cy + 0.5f * nh;
        parea[t] = nw * nh;
    } else if (t < 128) {
        const int j = t - 64;
        const float* gb = bboxes + ((size_t)b * NBOX + j) * 5;
        const float x1 = gb[0], y1 = gb[1], x2v = gb[2], y2v = gb[3];
        bx1[j] = x1; by1[j] = y1; bx2s[j] = x2v; by2s[j] = y2v;
        bga[j] = (x2v - x1) * (y2v - y1);
    }
    __syncthreads();

    const int p  = t >> 2;
    const int jb = (t & 3) * 16;
    const float Px1 = prx1[p], Py1 = pry1[p], Px2 = prx2[p], Py2 = pry2[p];
    const float pa = parea[p];
    float* dst = iou_out + ((size_t)blk * 64 + p) * 64 + jb;
#pragma unroll
    for (int q = 0; q < 4; ++q) {
        f32x4 o4;
#pragma unroll
        for (int e = 0; e < 4; ++e) {
            const int j = jb + q * 4 + e;
            const float iw = fminf(Px2, bx2s[j]) - fmaxf(Px1, bx1[j]);
            const float ih = fminf(Py2, by2s[j]) - fmaxf(Py1, by1[j]);
            const float inter = fmaxf(iw, 0.f) * fmaxf(ih, 0.f);
            o4[e] = inter * __builtin_amdgcn_rcpf(bga[j] + pa - inter);
        }
        __builtin_nontemporal_store(o4, (f32x4*)(dst + q * 4));
    }
}

__global__ __launch_bounds__(256) void class_kernel(
    const float* __restrict__ x2, const int* __restrict__ pos_idx,
    float* __restrict__ cls_out)
{
    const int g = blockIdx.x * 256 + threadIdx.x;   // 0 .. 40959
    const int m = g / CNUM;
    const int c = g - m * CNUM;
    const int idx = pos_idx[m];
    const int bi  = idx / AHW;
    const int hw  = idx % HW;
    cls_out[g] = x2[((size_t)bi * OC + 45 + c) * HW + hw];
}

__global__ __launch_bounds__(1024) void loss_kernel(
    const float* __restrict__ x2, const float* __restrict__ gt_off,
    const int* __restrict__ pos_idx, const int* __restrict__ neg_idx,
    float* __restrict__ out0)
{
    const int t = threadIdx.x;
    float csum = 0.f, rsum = 0.f;
    for (int m = t; m < M_; m += 1024) {
        const int idx = pos_idx[m];
        const int bi = idx / AHW;
        const int rr = idx - bi * AHW;
        const int a  = rr / HW;
        const int hw = rr - a * HW;
        const float* xb = x2 + ((size_t)bi * OC + 5 * a) * HW + hw;
        const float s = 1.f / (1.f + __expf(-xb[0]));
        csum += (s - 1.f) * (s - 1.f);
#pragma unroll
        for (int k = 0; k < 4; ++k) {
            const float d = xb[(size_t)(k + 1) * HW] - gt_off[m * 4 + k];
            rsum += d * d;
        }
    }
    for (int m = t; m < M_; m += 1024) {
        const int idx = neg_idx[m];
        const int bi = idx / AHW;
        const int rr = idx - bi * AHW;
        const int a  = rr / HW;
        const int hw = rr - a * HW;
        const float s = 1.f / (1.f + __expf(-x2[((size_t)bi * OC + 5 * a) * HW + hw]));
        csum += s * s;
    }
    __shared__ float red[32];
#pragma unroll
    for (int off = 32; off > 0; off >>= 1) {
        csum += __shfl_down(csum, off, 64);
        rsum += __shfl_down(rsum, off, 64);
    }
    if ((t & 63) == 0) { red[t >> 6] = csum; red[16 + (t >> 6)] = rsum; }
    __syncthreads();
    if (t == 0) {
        float c = 0.f, rg = 0.f;
#pragma unroll
        for (int i = 0; i < 16; ++i) { c += red[i]; rg += red[16 + i]; }
        out0[0] = c / (2.f * (float)M_) + rg / (float)M_;
    }
}

extern "C" void kernel_launch(void* const* d_in, const int* in_sizes, int n_in,
                              void* d_out, int out_size, void* d_ws, size_t ws_size,
                              hipStream_t stream) {
    (void)in_sizes; (void)n_in; (void)out_size; (void)ws_size;
    const float* features = (const float*)d_in[0];
    const float* w1       = (const float*)d_in[1];
    const float* b1       = (const float*)d_in[2];
    const float* w2       = (const float*)d_in[3];
    const float* b2       = (const float*)d_in[4];
    const float* anc      = (const float*)d_in[5];
    const float* grid     = (const float*)d_in[6];
    const float* bboxes   = (const float*)d_in[7];
    const float* gt_off   = (const float*)d_in[8];
    const int*   pos_idx  = (const int*)d_in[9];
    const int*   neg_idx  = (const int*)d_in[10];
    float* out = (float*)d_out;

    char* wsb = (char*)d_ws;
    float* x2 = (float*)wsb;                                  // 26,091,520 B
    _Float16* w1h = (_Float16*)(wsb + X2_BYTES);              // 131,072 B
    _Float16* w2h = w1h + 65536;                              // 33,280 B

    prep_kernel<<<256, 256, 0, stream>>>(w1, w2, w1h, w2h);
    conv_fused_kernel<<<B_ * NTILE, 256, 0, stream>>>(features, w1h, b1, w2h, b2, x2);
    iou_kernel<<<B_ * A_ * NTILE, 256, 0, stream>>>(x2, anc, grid, bboxes, out + 1);
    class_kernel<<<(M_ * CNUM) / 256, 256, 0, stream>>>(x2, pos_idx, out + 1 + IOU_N);
    loss_kernel<<<1, 1024, 0, stream>>>(x2, gt_off, pos_idx, neg_idx, out);
}

// Round 4
// 416.859 us; speedup vs baseline: 2.1658x; 1.5679x over previous
//
#include <hip/hip_runtime.h>
#include <math.h>

#define B_    32
#define CIN   256
#define HID   256
#define OC    65
#define A_    9
#define H_    56
#define W_    56
#define HW    3136
#define AHW   28224
#define NBOX  64
#define M_    2048
#define CNUM  20
#define NTILE 49         // HW / 64

#define IOU_N ((size_t)B_ * AHW * NBOX)      // 57,802,752
#define X2_BYTES ((size_t)B_ * OC * HW * 4)  // 26,091,520

typedef _Float16 half8 __attribute__((ext_vector_type(8)));
typedef float f32x16 __attribute__((ext_vector_type(16)));
typedef float f32x4  __attribute__((ext_vector_type(4)));

__device__ __forceinline__ unsigned int pkh(float a, float b) {
    _Float16 ha = (_Float16)a, hb = (_Float16)b;
    unsigned short ua = __builtin_bit_cast(unsigned short, ha);
    unsigned short ub = __builtin_bit_cast(unsigned short, hb);
    return (unsigned int)ua | ((unsigned int)ub << 16);
}

__global__ __launch_bounds__(256) void prep_kernel(
    const float* __restrict__ w1, const float* __restrict__ w2,
    _Float16* __restrict__ w1h, _Float16* __restrict__ w2h)
{
    const int i = blockIdx.x * 256 + threadIdx.x;
    if (i < 65536) w1h[i] = (_Float16)w1[i];
    if (i < 16640) w2h[i] = (_Float16)w2[i];
}

// Fused conv1 + conv2 via fp16 MFMA. Block = (batch, 64-px tile), 4 waves.
// 3 barriers total: stage ALL features (32KB, fragment order) -> conv1 MFMA
// -> repack hidden into aliased LDS -> conv2 MFMA -> store.
__global__ __launch_bounds__(256) void conv_fused_kernel(
    const float* __restrict__ features, const _Float16* __restrict__ w1h,
    const float* __restrict__ b1, const _Float16* __restrict__ w2h,
    const float* __restrict__ b2, float* __restrict__ x2)
{
    __shared__ _Float16 lds_h[16384];   // 32 KB: feat fragments, then aliased as hidf
    __shared__ float bias_s[HID];       // 1 KB

    _Float16* featAll = lds_h;          // [chunk c][(ks*2+pt)*64+lane][8]
    _Float16* hidf    = lds_h;          // [ks2*4+pt2][64 frag][8]  (alias, after barrier)

    const int t    = threadIdx.x;
    const int lane = t & 63;
    const int w    = t >> 6;
    const int bid  = blockIdx.x;
    const int b    = bid / NTILE;
    const int p0   = (bid - b * NTILE) * 64;
    const float* fbase = features + (size_t)b * CIN * HW + p0;

    bias_s[t] = b1[t];

    // staging coords (constant per thread)
    const int pstage = (t & 15) * 4;        // pixel base (4 px per thread)
    const int kk     = (t >> 4) * 2;        // k-row pair within a 32-k chunk
    const int ksS    = kk >> 4;
    const int gS     = (kk >> 3) & 1;
    const int j0     = kk & 7;              // even
    const int m31    = lane & 31;
    const int ghalf  = lane >> 5;

    // ---- stage ALL 8 feature chunks, fp32->fp16, fragment order; no barriers ----
#pragma unroll
    for (int c = 0; c < 8; ++c) {
        const float4 r0 = *(const float4*)(fbase + (size_t)(c * 32 + kk) * HW + pstage);
        const float4 r1 = *(const float4*)(fbase + (size_t)(c * 32 + kk + 1) * HW + pstage);
        const float a0[4] = {r0.x, r0.y, r0.z, r0.w};
        const float a1[4] = {r1.x, r1.y, r1.z, r1.w};
#pragma unroll
        for (int e = 0; e < 4; ++e) {
            const int p     = pstage + e;
            const int lane2 = gS * 32 + (p & 31);
            const int pt    = p >> 5;
            const int frag  = (ksS * 2 + pt) * 64 + lane2;
            *(unsigned int*)&featAll[c * 2048 + frag * 8 + j0] = pkh(a0[e], a1[e]);
        }
    }
    __syncthreads();

    // ---- conv1: wave w -> hidden rows [64w, 64w+64), 2x2 32x32x16 accums ----
    f32x16 facc[2][2];
#pragma unroll
    for (int ot = 0; ot < 2; ++ot)
#pragma unroll
        for (int pt = 0; pt < 2; ++pt)
#pragma unroll
            for (int e = 0; e < 16; ++e) facc[ot][pt][e] = 0.f;

#pragma unroll 2
    for (int c = 0; c < 8; ++c) {
#pragma unroll
        for (int ks = 0; ks < 2; ++ks) {
            half8 af[2];
#pragma unroll
            for (int ot = 0; ot < 2; ++ot) {
                const int o  = w * 64 + ot * 32 + m31;
                const int kA = c * 32 + ks * 16 + ghalf * 8;
                af[ot] = *(const half8*)(w1h + (size_t)o * CIN + kA);
            }
#pragma unroll
            for (int pt = 0; pt < 2; ++pt) {
                const half8 bf = *(const half8*)&featAll[c * 2048 + ((ks * 2 + pt) * 64 + lane) * 8];
                facc[0][pt] = __builtin_amdgcn_mfma_f32_32x32x16_f16(af[0], bf, facc[0][pt], 0, 0, 0);
                facc[1][pt] = __builtin_amdgcn_mfma_f32_32x32x16_f16(af[1], bf, facc[1][pt], 0, 0, 0);
            }
        }
    }
    __syncthreads();   // all feat reads done; safe to alias as hidf

    // ---- bias + leaky relu, repack to conv2 B-fragment order ----
    const int col = lane & 31;
#pragma unroll
    for (int ot = 0; ot < 2; ++ot) {
        const int ks2 = w * 2 + ot;
#pragma unroll
        for (int pt = 0; pt < 2; ++pt) {
            const int pt2 = pt * 2 + (col >> 4);
            const int n15 = col & 15;
#pragma unroll
            for (int q = 0; q < 4; ++q) {
                float hv[4];
#pragma unroll
                for (int i = 0; i < 4; ++i) {
                    const int row = i + 8 * q + 4 * ghalf;
                    float v = facc[ot][pt][q * 4 + i] + bias_s[w * 64 + ot * 32 + row];
                    hv[i] = v < 0.f ? 0.01f * v : v;
                }
                const int frag = (ks2 * 4 + pt2) * 64 + (q * 16 + n15);
                *(unsigned int*)&hidf[frag * 8 + 4 * ghalf]     = pkh(hv[0], hv[1]);
                *(unsigned int*)&hidf[frag * 8 + 4 * ghalf + 2] = pkh(hv[2], hv[3]);
            }
        }
    }
    __syncthreads();

    // ---- conv2 via 16x16x32 MFMA; wave w owns pixels [16w, 16w+16) ----
    f32x4 c2[5];
#pragma unroll
    for (int rt = 0; rt < 5; ++rt)
#pragma unroll
        for (int e = 0; e < 4; ++e) c2[rt][e] = 0.f;

    const int m16 = lane & 15;
    const int kgr = lane >> 4;
#pragma unroll 2
    for (int ks2 = 0; ks2 < 8; ++ks2) {
        const half8 bf = *(const half8*)&hidf[((ks2 * 4 + w) * 64 + lane) * 8];
#pragma unroll
        for (int rt = 0; rt < 5; ++rt) {
            const int o2 = rt * 16 + m16;
            half8 af;
            if (o2 < OC) {
                const int kA = ks2 * 32 + kgr * 8;
                af = *(const half8*)(w2h + (size_t)o2 * HID + kA);
            } else {
#pragma unroll
                for (int e = 0; e < 8; ++e) af[e] = (_Float16)0.f;
            }
            c2[rt] = __builtin_amdgcn_mfma_f32_16x16x32_f16(af, bf, c2[rt], 0, 0, 0);
        }
    }

    float* xb = x2 + (size_t)b * OC * HW + p0 + w * 16 + m16;
#pragma unroll
    for (int rt = 0; rt < 5; ++rt) {
#pragma unroll
        for (int r = 0; r < 4; ++r) {
            const int o2 = rt * 16 + kgr * 4 + r;
            if (o2 < OC) xb[(size_t)o2 * HW] = c2[rt][r] + b2[o2];
        }
    }
}

// Block = 64 proposals (one (b,a), consecutive hw) x 64 boxes.
// Lane (pr=lane>>4, j0=(lane&15)*4); row p = w*16 + q*4 + pr.
// Per store instruction the wave writes one CONTIGUOUS 1KB span (lane*16B).
__global__ __launch_bounds__(256) void iou_kernel(
    const float* __restrict__ x2, const float* __restrict__ anc,
    const float* __restrict__ grid, const float* __restrict__ bboxes,
    float* __restrict__ iou_out)
{
    __shared__ float prx1[64], pry1[64], prx2[64], pry2[64], parea[64];
    __shared__ float bx1[64], by1[64], bx2s[64], by2s[64], bga[64];

    const int t    = threadIdx.x;
    const int blk  = blockIdx.x;
    const int b    = blk / (A_ * NTILE);
    const int r    = blk - b * (A_ * NTILE);
    const int a    = r / NTILE;
    const int tile = r - a * NTILE;
    const int hw0  = tile * 64;

    if (t < 64) {
        const int hw = hw0 + t;
        const int h  = hw / W_;
        const int wv = hw - h * W_;
        const float* xb = x2 + ((size_t)b * OC + 5 * a) * HW + hw;
        const float tx = xb[HW], ty = xb[2 * HW], tw = xb[3 * HW], th = xb[4 * HW];
        const size_t gi = (((size_t)b * H_ + h) * W_ + wv) * 2;
        const float gx = grid[gi], gy = grid[gi + 1];
        const float nw = anc[2 * a]     * __expf(tw);
        const float nh = anc[2 * a + 1] * __expf(th);
        const float cx = gx + tx, cy = gy + ty;
        prx1[t] = cx - 0.5f * nw; pry1[t] = cy - 0.5f * nh;
        prx2[t] = cx + 0.5f * nw; pry2[t] = cy + 0.5f * nh;
        parea[t] = nw * nh;
    } else if (t < 128) {
        const int j = t - 64;
        const float* gb = bboxes + ((size_t)b * NBOX + j) * 5;
        const float x1 = gb[0], y1 = gb[1], x2v = gb[2], y2v = gb[3];
        bx1[j] = x1; by1[j] = y1; bx2s[j] = x2v; by2s[j] = y2v;
        bga[j] = (x2v - x1) * (y2v - y1);
    }
    __syncthreads();

    const int lane = t & 63;
    const int w    = t >> 6;
    const int pr   = lane >> 4;
    const int j0   = (lane & 15) * 4;

    // boxes fixed per lane: hoist to registers
    float Bx1[4], By1[4], Bx2[4], By2[4], Ba[4];
#pragma unroll
    for (int e = 0; e < 4; ++e) {
        Bx1[e] = bx1[j0 + e]; By1[e] = by1[j0 + e];
        Bx2[e] = bx2s[j0 + e]; By2[e] = by2s[j0 + e];
        Ba[e]  = bga[j0 + e];
    }

    float* dstbase = iou_out + (size_t)blk * 4096;
#pragma unroll
    for (int q = 0; q < 4; ++q) {
        const int p = w * 16 + q * 4 + pr;
        const float Px1 = prx1[p], Py1 = pry1[p], Px2 = prx2[p], Py2 = pry2[p];
        const float pa = parea[p];
        f32x4 o4;
#pragma unroll
        for (int e = 0; e < 4; ++e) {
            const float iw = fminf(Px2, Bx2[e]) - fmaxf(Px1, Bx1[e]);
            const float ih = fminf(Py2, By2[e]) - fmaxf(Py1, By1[e]);
            const float inter = fmaxf(iw, 0.f) * fmaxf(ih, 0.f);
            o4[e] = inter * __builtin_amdgcn_rcpf(Ba[e] + pa - inter);
        }
        *(f32x4*)(dstbase + p * 64 + j0) = o4;
    }
}

__global__ __launch_bounds__(256) void class_kernel(
    const float* __restrict__ x2, const int* __restrict__ pos_idx,
    float* __restrict__ cls_out)
{
    const int g = blockIdx.x * 256 + threadIdx.x;   // 0 .. 40959
    const int m = g / CNUM;
    const int c = g - m * CNUM;
    const int idx = pos_idx[m];
    const int bi  = idx / AHW;
    const int hw  = idx % HW;
    cls_out[g] = x2[((size_t)bi * OC + 45 + c) * HW + hw];
}

__global__ __launch_bounds__(1024) void loss_kernel(
    const float* __restrict__ x2, const float* __restrict__ gt_off,
    const int* __restrict__ pos_idx, const int* __restrict__ neg_idx,
    float* __restrict__ out0)
{
    const int t = threadIdx.x;
    float csum = 0.f, rsum = 0.f;
    for (int m = t; m < M_; m += 1024) {
        const int idx = pos_idx[m];
        const int bi = idx / AHW;
        const int rr = idx - bi * AHW;
        const int a  = rr / HW;
        const int hw = rr - a * HW;
        const float* xb = x2 + ((size_t)bi * OC + 5 * a) * HW + hw;
        const float s = 1.f / (1.f + __expf(-xb[0]));
        csum += (s - 1.f) * (s - 1.f);
#pragma unroll
        for (int k = 0; k < 4; ++k) {
            const float d = xb[(size_t)(k + 1) * HW] - gt_off[m * 4 + k];
            rsum += d * d;
        }
    }
    for (int m = t; m < M_; m += 1024) {
        const int idx = neg_idx[m];
        const int bi = idx / AHW;
        const int rr = idx - bi * AHW;
        const int a  = rr / HW;
        const int hw = rr - a * HW;
        const float s = 1.f / (1.f + __expf(-x2[((size_t)bi * OC + 5 * a) * HW + hw]));
        csum += s * s;
    }
    __shared__ float red[32];
#pragma unroll
    for (int off = 32; off > 0; off >>= 1) {
        csum += __shfl_down(csum, off, 64);
        rsum += __shfl_down(rsum, off, 64);
    }
    if ((t & 63) == 0) { red[t >> 6] = csum; red[16 + (t >> 6)] = rsum; }
    __syncthreads();
    if (t == 0) {
        float c = 0.f, rg = 0.f;
#pragma unroll
        for (int i = 0; i < 16; ++i) { c += red[i]; rg += red[16 + i]; }
        out0[0] = c / (2.f * (float)M_) + rg / (float)M_;
    }
}

extern "C" void kernel_launch(void* const* d_in, const int* in_sizes, int n_in,
                              void* d_out, int out_size, void* d_ws, size_t ws_size,
                              hipStream_t stream) {
    (void)in_sizes; (void)n_in; (void)out_size; (void)ws_size;
    const float* features = (const float*)d_in[0];
    const float* w1       = (const float*)d_in[1];
    const float* b1       = (const float*)d_in[2];
    const float* w2       = (const float*)d_in[3];
    const float* b2       = (const float*)d_in[4];
    const float* anc      = (const float*)d_in[5];
    const float* grid     = (const float*)d_in[6];
    const float* bboxes   = (const float*)d_in[7];
    const float* gt_off   = (const float*)d_in[8];
    const int*   pos_idx  = (const int*)d_in[9];
    const int*   neg_idx  = (const int*)d_in[10];
    float* out = (float*)d_out;

    char* wsb = (char*)d_ws;
    float* x2 = (float*)wsb;                                  // 26,091,520 B
    _Float16* w1h = (_Float16*)(wsb + X2_BYTES);              // 131,072 B
    _Float16* w2h = w1h + 65536;                              // 33,280 B

    prep_kernel<<<256, 256, 0, stream>>>(w1, w2, w1h, w2h);
    conv_fused_kernel<<<B_ * NTILE, 256, 0, stream>>>(features, w1h, b1, w2h, b2, x2);
    iou_kernel<<<B_ * A_ * NTILE, 256, 0, stream>>>(x2, anc, grid, bboxes, out + 1);
    class_kernel<<<(M_ * CNUM) / 256, 256, 0, stream>>>(x2, pos_idx, out + 1 + IOU_N);
    loss_kernel<<<1, 1024, 0, stream>>>(x2, gt_off, pos_idx, neg_idx, out);
}

// Round 5
// 390.315 us; speedup vs baseline: 2.3131x; 1.0680x over previous
//
#include <hip/hip_runtime.h>
#include <math.h>

#define B_    32
#define CIN   256
#define HID   256
#define OC    65
#define A_    9
#define H_    56
#define W_    56
#define HW    3136
#define AHW   28224
#define NBOX  64
#define M_    2048
#define CNUM  20
#define NTILE 49         // HW / 64

#define IOU_N ((size_t)B_ * AHW * NBOX)      // 57,802,752
#define X2_BYTES ((size_t)B_ * OC * HW * 4)  // 26,091,520

// padded LDS fragment offset (halfwords): +16B every 8 fragment rows.
// breaks the dword-stride-16 pattern that caused 8-way staging-write conflicts.
#define FOFF(frag) (((frag) << 3) + ((((frag) >> 3)) << 3))

typedef _Float16 half8 __attribute__((ext_vector_type(8)));
typedef float f32x16 __attribute__((ext_vector_type(16)));
typedef float f32x4  __attribute__((ext_vector_type(4)));

__device__ __forceinline__ unsigned int pkh(float a, float b) {
    _Float16 ha = (_Float16)a, hb = (_Float16)b;
    unsigned short ua = __builtin_bit_cast(unsigned short, ha);
    unsigned short ub = __builtin_bit_cast(unsigned short, hb);
    return (unsigned int)ua | ((unsigned int)ub << 16);
}

// Pre-swizzle weights into MFMA A-fragment order (fp16).
// w1s[((ob*16+kc)*64+lane)*8+e] = w1[ob*32+(lane&31)][kc*16+(lane>>5)*8+e]   (32x32x16 A)
// w2s[((rt*8+ks2)*64+lane)*8+e] = w2[rt*16+(lane&15)][ks2*32+(lane>>4)*8+e]  (16x16x32 A, rows>=65 zero)
__global__ __launch_bounds__(256) void prep_kernel(
    const float* __restrict__ w1, const float* __restrict__ w2,
    _Float16* __restrict__ w1s, _Float16* __restrict__ w2s)
{
    const int f = blockIdx.x * 256 + threadIdx.x;   // 0..65535
    {
        const int e    = f & 7;
        const int lane = (f >> 3) & 63;
        const int kc   = (f >> 9) & 15;
        const int ob   = f >> 13;
        const int row  = ob * 32 + (lane & 31);
        const int k    = kc * 16 + (lane >> 5) * 8 + e;
        w1s[f] = (_Float16)w1[row * CIN + k];
    }
    if (f < 20480) {
        const int e    = f & 7;
        const int lane = (f >> 3) & 63;
        const int ks2  = (f >> 9) & 7;
        const int rt   = f >> 12;
        const int row  = rt * 16 + (lane & 15);
        const int k    = ks2 * 32 + (lane >> 4) * 8 + e;
        w2s[f] = (row < OC) ? (_Float16)w2[row * HID + k] : (_Float16)0.f;
    }
}

// Fused conv1 + conv2 via fp16 MFMA. Block = (batch, 64-px tile), 4 waves, 3 barriers.
// All weight A-fragments are contiguous 1KB/wave loads from pre-swizzled w1s/w2s.
__global__ __launch_bounds__(256) void conv_fused_kernel(
    const float* __restrict__ features, const _Float16* __restrict__ w1s,
    const float* __restrict__ b1, const _Float16* __restrict__ w2s,
    const float* __restrict__ b2, float* __restrict__ x2)
{
    __shared__ _Float16 lds_h[18432];   // 36 KB padded: feat fragments, aliased as hidf
    __shared__ float bias_s[HID];       // 1 KB

    _Float16* featAll = lds_h;
    _Float16* hidf    = lds_h;

    const int t    = threadIdx.x;
    const int lane = t & 63;
    const int w    = t >> 6;
    const int bid  = blockIdx.x;
    const int b    = bid / NTILE;
    const int p0   = (bid - b * NTILE) * 64;
    const float* fbase = features + (size_t)b * CIN * HW + p0;

    bias_s[t] = b1[t];

    // staging coords
    const int pstage = (t & 15) * 4;        // pixel base (4 px/thread)
    const int kk     = (t >> 4) * 2;        // k-row pair within a 32-k chunk
    const int ksS    = kk >> 4;
    const int gS     = (kk >> 3) & 1;
    const int j0     = kk & 7;              // even halfword offset
    const int ghalf  = lane >> 5;

    // ---- stage ALL 8 feature chunks, fp32->fp16, padded fragment order ----
#pragma unroll
    for (int c = 0; c < 8; ++c) {
        const float4 r0 = *(const float4*)(fbase + (size_t)(c * 32 + kk) * HW + pstage);
        const float4 r1 = *(const float4*)(fbase + (size_t)(c * 32 + kk + 1) * HW + pstage);
        const float a0[4] = {r0.x, r0.y, r0.z, r0.w};
        const float a1[4] = {r1.x, r1.y, r1.z, r1.w};
#pragma unroll
        for (int e = 0; e < 4; ++e) {
            const int p     = pstage + e;
            const int lane2 = gS * 32 + (p & 31);
            const int pt    = p >> 5;
            const int frag  = c * 256 + (ksS * 2 + pt) * 64 + lane2;
            *(unsigned int*)&featAll[FOFF(frag) + j0] = pkh(a0[e], a1[e]);
        }
    }
    __syncthreads();

    // ---- conv1: wave w -> hidden rows [64w,64w+64), 2x2 32x32x16 accums ----
    f32x16 facc[2][2];
#pragma unroll
    for (int ot = 0; ot < 2; ++ot)
#pragma unroll
        for (int pt = 0; pt < 2; ++pt)
#pragma unroll
            for (int e = 0; e < 16; ++e) facc[ot][pt][e] = 0.f;

    // double-buffered A-fragment prefetch (contiguous 1KB/wave loads)
    half8 afb[2][2][2];   // [buf][ks][ot]
#pragma unroll
    for (int ks = 0; ks < 2; ++ks)
#pragma unroll
        for (int ot = 0; ot < 2; ++ot)
            afb[0][ks][ot] = *(const half8*)(w1s + ((size_t)((w * 2 + ot) * 16 + ks) * 64 + lane) * 8);

#pragma unroll
    for (int c = 0; c < 8; ++c) {
        if (c < 7) {
#pragma unroll
            for (int ks = 0; ks < 2; ++ks)
#pragma unroll
                for (int ot = 0; ot < 2; ++ot)
                    afb[(c + 1) & 1][ks][ot] =
                        *(const half8*)(w1s + ((size_t)((w * 2 + ot) * 16 + (c + 1) * 2 + ks) * 64 + lane) * 8);
        }
#pragma unroll
        for (int ks = 0; ks < 2; ++ks) {
#pragma unroll
            for (int pt = 0; pt < 2; ++pt) {
                const half8 bf = *(const half8*)&featAll[FOFF(c * 256 + (ks * 2 + pt) * 64 + lane)];
                facc[0][pt] = __builtin_amdgcn_mfma_f32_32x32x16_f16(afb[c & 1][ks][0], bf, facc[0][pt], 0, 0, 0);
                facc[1][pt] = __builtin_amdgcn_mfma_f32_32x32x16_f16(afb[c & 1][ks][1], bf, facc[1][pt], 0, 0, 0);
            }
        }
    }
    __syncthreads();   // all feat reads done; alias as hidf

    // ---- bias + leaky relu, repack to conv2 B-fragment order ----
    const int col = lane & 31;
#pragma unroll
    for (int ot = 0; ot < 2; ++ot) {
        const int ks2 = w * 2 + ot;
#pragma unroll
        for (int pt = 0; pt < 2; ++pt) {
            const int pt2 = pt * 2 + (col >> 4);
            const int n15 = col & 15;
#pragma unroll
            for (int q = 0; q < 4; ++q) {
                float hv[4];
#pragma unroll
                for (int i = 0; i < 4; ++i) {
                    const int row = i + 8 * q + 4 * ghalf;
                    float v = facc[ot][pt][q * 4 + i] + bias_s[w * 64 + ot * 32 + row];
                    hv[i] = v < 0.f ? 0.01f * v : v;
                }
                const int frag = (ks2 * 4 + pt2) * 64 + (q * 16 + n15);
                *(unsigned int*)&hidf[FOFF(frag) + 4 * ghalf]     = pkh(hv[0], hv[1]);
                *(unsigned int*)&hidf[FOFF(frag) + 4 * ghalf + 2] = pkh(hv[2], hv[3]);
            }
        }
    }
    __syncthreads();

    // ---- conv2 via 16x16x32 MFMA; wave w owns pixels [16w,16w+16) ----
    f32x4 c2[5];
#pragma unroll
    for (int rt = 0; rt < 5; ++rt)
#pragma unroll
        for (int e = 0; e < 4; ++e) c2[rt][e] = 0.f;

    const int m16 = lane & 15;
    const int kgr = lane >> 4;
#pragma unroll 2
    for (int ks2 = 0; ks2 < 8; ++ks2) {
        const half8 bf = *(const half8*)&hidf[FOFF((ks2 * 4 + w) * 64 + lane)];
#pragma unroll
        for (int rt = 0; rt < 5; ++rt) {
            const half8 af = *(const half8*)(w2s + ((size_t)(rt * 8 + ks2) * 64 + lane) * 8);
            c2[rt] = __builtin_amdgcn_mfma_f32_16x16x32_f16(af, bf, c2[rt], 0, 0, 0);
        }
    }

    float* xb = x2 + (size_t)b * OC * HW + p0 + w * 16 + m16;
#pragma unroll
    for (int rt = 0; rt < 5; ++rt) {
#pragma unroll
        for (int r = 0; r < 4; ++r) {
            const int o2 = rt * 16 + kgr * 4 + r;
            if (o2 < OC) xb[(size_t)o2 * HW] = c2[rt][r] + b2[o2];
        }
    }
}

// Block = 64 proposals (one (b,a), consecutive hw) x 64 boxes.
// Per store instruction the wave writes one contiguous 1KB span, nontemporal.
__global__ __launch_bounds__(256) void iou_kernel(
    const float* __restrict__ x2, const float* __restrict__ anc,
    const float* __restrict__ grid, const float* __restrict__ bboxes,
    float* __restrict__ iou_out)
{
    __shared__ float prx1[64], pry1[64], prx2[64], pry2[64], parea[64];
    __shared__ float bx1[64], by1[64], bx2s[64], by2s[64], bga[64];

    const int t    = threadIdx.x;
    const int blk  = blockIdx.x;
    const int b    = blk / (A_ * NTILE);
    const int r    = blk - b * (A_ * NTILE);
    const int a    = r / NTILE;
    const int tile = r - a * NTILE;
    const int hw0  = tile * 64;

    if (t < 64) {
        const int hw = hw0 + t;
        const int h  = hw / W_;
        const int wv = hw - h * W_;
        const float* xb = x2 + ((size_t)b * OC + 5 * a) * HW + hw;
        const float tx = xb[HW], ty = xb[2 * HW], tw = xb[3 * HW], th = xb[4 * HW];
        const size_t gi = (((size_t)b * H_ + h) * W_ + wv) * 2;
        const float gx = grid[gi], gy = grid[gi + 1];
        const float nw = anc[2 * a]     * __expf(tw);
        const float nh = anc[2 * a + 1] * __expf(th);
        const float cx = gx + tx, cy = gy + ty;
        prx1[t] = cx - 0.5f * nw; pry1[t] = cy - 0.5f * nh;
        prx2[t] = cx + 0.5f * nw; pry2[t] = cy + 0.5f * nh;
        parea[t] = nw * nh;
    } else if (t < 128) {
        const int j = t - 64;
        const float* gb = bboxes + ((size_t)b * NBOX + j) * 5;
        const float x1 = gb[0], y1 = gb[1], x2v = gb[2], y2v = gb[3];
        bx1[j] = x1; by1[j] = y1; bx2s[j] = x2v; by2s[j] = y2v;
        bga[j] = (x2v - x1) * (y2v - y1);
    }
    __syncthreads();

    const int lane = t & 63;
    const int w    = t >> 6;
    const int pr   = lane >> 4;
    const int j0   = (lane & 15) * 4;

    float Bx1[4], By1[4], Bx2[4], By2[4], Ba[4];
#pragma unroll
    for (int e = 0; e < 4; ++e) {
        Bx1[e] = bx1[j0 + e]; By1[e] = by1[j0 + e];
        Bx2[e] = bx2s[j0 + e]; By2[e] = by2s[j0 + e];
        Ba[e]  = bga[j0 + e];
    }

    float* dstbase = iou_out + (size_t)blk * 4096;
#pragma unroll
    for (int q = 0; q < 4; ++q) {
        const int p = w * 16 + q * 4 + pr;
        const float Px1 = prx1[p], Py1 = pry1[p], Px2 = prx2[p], Py2 = pry2[p];
        const float pa = parea[p];
        f32x4 o4;
#pragma unroll
        for (int e = 0; e < 4; ++e) {
            const float iw = fminf(Px2, Bx2[e]) - fmaxf(Px1, Bx1[e]);
            const float ih = fminf(Py2, By2[e]) - fmaxf(Py1, By1[e]);
            const float inter = fmaxf(iw, 0.f) * fmaxf(ih, 0.f);
            o4[e] = inter * __builtin_amdgcn_rcpf(Ba[e] + pa - inter);
        }
        __builtin_nontemporal_store(o4, (f32x4*)(dstbase + p * 64 + j0));
    }
}

// blocks 0..159: class_pos gather; block 160: loss reduction.
__global__ __launch_bounds__(256) void tail_kernel(
    const float* __restrict__ x2, const int* __restrict__ pos_idx,
    const int* __restrict__ neg_idx, const float* __restrict__ gt_off,
    float* __restrict__ cls_out, float* __restrict__ out0)
{
    const int t = threadIdx.x;
    if (blockIdx.x < 160) {
        const int g = blockIdx.x * 256 + t;   // 0..40959
        const int m = g / CNUM;
        const int c = g - m * CNUM;
        const int idx = pos_idx[m];
        const int bi  = idx / AHW;
        const int hw  = idx % HW;
        cls_out[g] = x2[((size_t)bi * OC + 45 + c) * HW + hw];
        return;
    }
    float csum = 0.f, rsum = 0.f;
    for (int m = t; m < M_; m += 256) {
        const int idx = pos_idx[m];
        const int bi = idx / AHW;
        const int rr = idx - bi * AHW;
        const int a  = rr / HW;
        const int hw = rr - a * HW;
        const float* xb = x2 + ((size_t)bi * OC + 5 * a) * HW + hw;
        const float s = 1.f / (1.f + __expf(-xb[0]));
        csum += (s - 1.f) * (s - 1.f);
#pragma unroll
        for (int k = 0; k < 4; ++k) {
            const float d = xb[(size_t)(k + 1) * HW] - gt_off[m * 4 + k];
            rsum += d * d;
        }
    }
    for (int m = t; m < M_; m += 256) {
        const int idx = neg_idx[m];
        const int bi = idx / AHW;
        const int rr = idx - bi * AHW;
        const int a  = rr / HW;
        const int hw = rr - a * HW;
        const float s = 1.f / (1.f + __expf(-x2[((size_t)bi * OC + 5 * a) * HW + hw]));
        csum += s * s;
    }
    __shared__ float red[8];
#pragma unroll
    for (int off = 32; off > 0; off >>= 1) {
        csum += __shfl_down(csum, off, 64);
        rsum += __shfl_down(rsum, off, 64);
    }
    if ((t & 63) == 0) { red[t >> 6] = csum; red[4 + (t >> 6)] = rsum; }
    __syncthreads();
    if (t == 0) {
        const float c = red[0] + red[1] + red[2] + red[3];
        const float rg = red[4] + red[5] + red[6] + red[7];
        out0[0] = c / (2.f * (float)M_) + rg / (float)M_;
    }
}

extern "C" void kernel_launch(void* const* d_in, const int* in_sizes, int n_in,
                              void* d_out, int out_size, void* d_ws, size_t ws_size,
                              hipStream_t stream) {
    (void)in_sizes; (void)n_in; (void)out_size; (void)ws_size;
    const float* features = (const float*)d_in[0];
    const float* w1       = (const float*)d_in[1];
    const float* b1       = (const float*)d_in[2];
    const float* w2       = (const float*)d_in[3];
    const float* b2       = (const float*)d_in[4];
    const float* anc      = (const float*)d_in[5];
    const float* grid     = (const float*)d_in[6];
    const float* bboxes   = (const float*)d_in[7];
    const float* gt_off   = (const float*)d_in[8];
    const int*   pos_idx  = (const int*)d_in[9];
    const int*   neg_idx  = (const int*)d_in[10];
    float* out = (float*)d_out;

    char* wsb = (char*)d_ws;
    float* x2 = (float*)wsb;                                  // 26,091,520 B
    _Float16* w1s = (_Float16*)(wsb + X2_BYTES);              // 131,072 B
    _Float16* w2s = w1s + 65536;                              // 40,960 B

    prep_kernel<<<256, 256, 0, stream>>>(w1, w2, w1s, w2s);
    conv_fused_kernel<<<B_ * NTILE, 256, 0, stream>>>(features, w1s, b1, w2s, b2, x2);
    iou_kernel<<<B_ * A_ * NTILE, 256, 0, stream>>>(x2, anc, grid, bboxes, out + 1);
    tail_kernel<<<161, 256, 0, stream>>>(x2, pos_idx, neg_idx, gt_off, out + 1 + IOU_N, out);
}

// Round 6
// 386.605 us; speedup vs baseline: 2.3353x; 1.0096x over previous
//
#include <hip/hip_runtime.h>
#include <math.h>

#define B_    32
#define CIN   256
#define HID   256
#define OC    65
#define A_    9
#define H_    56
#define W_    56
#define HW    3136
#define AHW   28224
#define NBOX  64
#define M_    2048
#define CNUM  20
#define NTILE 49         // HW / 64

#define IOU_N ((size_t)B_ * AHW * NBOX)      // 57,802,752
#define X2_BYTES ((size_t)B_ * OC * HW * 4)  // 26,091,520

// padded LDS fragment offset (halfwords): +16B every 8 fragment rows.
#define FOFF(frag) (((frag) << 3) + ((((frag) >> 3)) << 3))

typedef _Float16 half8 __attribute__((ext_vector_type(8)));
typedef float f32x16 __attribute__((ext_vector_type(16)));
typedef float f32x4  __attribute__((ext_vector_type(4)));

__device__ __forceinline__ unsigned int pkh(float a, float b) {
    _Float16 ha = (_Float16)a, hb = (_Float16)b;
    unsigned short ua = __builtin_bit_cast(unsigned short, ha);
    unsigned short ub = __builtin_bit_cast(unsigned short, hb);
    return (unsigned int)ua | ((unsigned int)ub << 16);
}

// Pre-swizzle weights into MFMA A-fragment order (fp16).
__global__ __launch_bounds__(256) void prep_kernel(
    const float* __restrict__ w1, const float* __restrict__ w2,
    _Float16* __restrict__ w1s, _Float16* __restrict__ w2s)
{
    const int f = blockIdx.x * 256 + threadIdx.x;   // 0..65535
    {
        const int e    = f & 7;
        const int lane = (f >> 3) & 63;
        const int kc   = (f >> 9) & 15;
        const int ob   = f >> 13;
        const int row  = ob * 32 + (lane & 31);
        const int k    = kc * 16 + (lane >> 5) * 8 + e;
        w1s[f] = (_Float16)w1[row * CIN + k];
    }
    if (f < 20480) {
        const int e    = f & 7;
        const int lane = (f >> 3) & 63;
        const int ks2  = (f >> 9) & 7;
        const int rt   = f >> 12;
        const int row  = rt * 16 + (lane & 15);
        const int k    = ks2 * 32 + (lane >> 4) * 8 + e;
        w2s[f] = (row < OC) ? (_Float16)w2[row * HID + k] : (_Float16)0.f;
    }
}

// Fused conv1 + conv2 + IoU. Block = (batch, 64-px tile), 4 waves.
// conv phases as before; epilogue keeps the 64x65 x2 tile in LDS, builds the
// 9x64 proposals, and streams the 64px x 9a x 64box IoU tile (147 KB) with
// contiguous 1KB-per-wave nontemporal stores.
__global__ __launch_bounds__(256) void conv_iou_kernel(
    const float* __restrict__ features, const _Float16* __restrict__ w1s,
    const float* __restrict__ b1, const _Float16* __restrict__ w2s,
    const float* __restrict__ b2, const float* __restrict__ anc,
    const float* __restrict__ bboxes, float* __restrict__ x2,
    float* __restrict__ iou_out)
{
    __shared__ _Float16 lds_h[18432];   // 36 KB: feat frags -> hidf -> x2tile+prop
    __shared__ float bias_s[HID];       // 1 KB
    __shared__ float boxs[5 * 64];      // 1.25 KB: x1,y1,x2,y2,area

    _Float16* featAll = lds_h;
    _Float16* hidf    = lds_h;
    float*    L       = (float*)lds_h;  // epilogue carve (9216 floats)
    float*    x2t     = L;              // 64*69 = 4416 floats (stride-69: conflict-free)
    float*    ppx1    = L + 4416;       // 576 each
    float*    ppy1    = L + 4992;
    float*    ppx2    = L + 5568;
    float*    ppy2    = L + 6144;
    float*    pare    = L + 6720;       // ends 7296

    const int t    = threadIdx.x;
    const int lane = t & 63;
    const int w    = t >> 6;
    const int bid  = blockIdx.x;
    const int b    = bid / NTILE;
    const int p0   = (bid - b * NTILE) * 64;
    const float* fbase = features + (size_t)b * CIN * HW + p0;

    bias_s[t] = b1[t];
    if (t < 64) {
        const float* gb = bboxes + ((size_t)b * NBOX + t) * 5;
        const float x1 = gb[0], y1 = gb[1], x2v = gb[2], y2v = gb[3];
        boxs[t] = x1; boxs[64 + t] = y1; boxs[128 + t] = x2v; boxs[192 + t] = y2v;
        boxs[256 + t] = (x2v - x1) * (y2v - y1);
    }

    // staging coords
    const int pstage = (t & 15) * 4;
    const int kk     = (t >> 4) * 2;
    const int ksS    = kk >> 4;
    const int gS     = (kk >> 3) & 1;
    const int j0h    = kk & 7;
    const int ghalf  = lane >> 5;

    // ---- stage ALL 8 feature chunks, fp32->fp16, padded fragment order ----
#pragma unroll
    for (int c = 0; c < 8; ++c) {
        const float4 r0 = *(const float4*)(fbase + (size_t)(c * 32 + kk) * HW + pstage);
        const float4 r1 = *(const float4*)(fbase + (size_t)(c * 32 + kk + 1) * HW + pstage);
        const float a0[4] = {r0.x, r0.y, r0.z, r0.w};
        const float a1[4] = {r1.x, r1.y, r1.z, r1.w};
#pragma unroll
        for (int e = 0; e < 4; ++e) {
            const int p     = pstage + e;
            const int lane2 = gS * 32 + (p & 31);
            const int pt    = p >> 5;
            const int frag  = c * 256 + (ksS * 2 + pt) * 64 + lane2;
            *(unsigned int*)&featAll[FOFF(frag) + j0h] = pkh(a0[e], a1[e]);
        }
    }
    __syncthreads();

    // ---- conv1: wave w -> hidden rows [64w,64w+64), 2x2 32x32x16 accums ----
    f32x16 facc[2][2];
#pragma unroll
    for (int ot = 0; ot < 2; ++ot)
#pragma unroll
        for (int pt = 0; pt < 2; ++pt)
#pragma unroll
            for (int e = 0; e < 16; ++e) facc[ot][pt][e] = 0.f;

    half8 afb[2][2][2];
#pragma unroll
    for (int ks = 0; ks < 2; ++ks)
#pragma unroll
        for (int ot = 0; ot < 2; ++ot)
            afb[0][ks][ot] = *(const half8*)(w1s + ((size_t)((w * 2 + ot) * 16 + ks) * 64 + lane) * 8);

#pragma unroll
    for (int c = 0; c < 8; ++c) {
        if (c < 7) {
#pragma unroll
            for (int ks = 0; ks < 2; ++ks)
#pragma unroll
                for (int ot = 0; ot < 2; ++ot)
                    afb[(c + 1) & 1][ks][ot] =
                        *(const half8*)(w1s + ((size_t)((w * 2 + ot) * 16 + (c + 1) * 2 + ks) * 64 + lane) * 8);
        }
#pragma unroll
        for (int ks = 0; ks < 2; ++ks) {
#pragma unroll
            for (int pt = 0; pt < 2; ++pt) {
                const half8 bf = *(const half8*)&featAll[FOFF(c * 256 + (ks * 2 + pt) * 64 + lane)];
                facc[0][pt] = __builtin_amdgcn_mfma_f32_32x32x16_f16(afb[c & 1][ks][0], bf, facc[0][pt], 0, 0, 0);
                facc[1][pt] = __builtin_amdgcn_mfma_f32_32x32x16_f16(afb[c & 1][ks][1], bf, facc[1][pt], 0, 0, 0);
            }
        }
    }
    __syncthreads();

    // ---- bias + leaky relu, repack to conv2 B-fragment order ----
    const int col = lane & 31;
#pragma unroll
    for (int ot = 0; ot < 2; ++ot) {
        const int ks2 = w * 2 + ot;
#pragma unroll
        for (int pt = 0; pt < 2; ++pt) {
            const int pt2 = pt * 2 + (col >> 4);
            const int n15 = col & 15;
#pragma unroll
            for (int q = 0; q < 4; ++q) {
                float hv[4];
#pragma unroll
                for (int i = 0; i < 4; ++i) {
                    const int row = i + 8 * q + 4 * ghalf;
                    float v = facc[ot][pt][q * 4 + i] + bias_s[w * 64 + ot * 32 + row];
                    hv[i] = v < 0.f ? 0.01f * v : v;
                }
                const int frag = (ks2 * 4 + pt2) * 64 + (q * 16 + n15);
                *(unsigned int*)&hidf[FOFF(frag) + 4 * ghalf]     = pkh(hv[0], hv[1]);
                *(unsigned int*)&hidf[FOFF(frag) + 4 * ghalf + 2] = pkh(hv[2], hv[3]);
            }
        }
    }
    __syncthreads();

    // ---- conv2 via 16x16x32 MFMA; wave w owns pixels [16w,16w+16) ----
    f32x4 c2[5];
#pragma unroll
    for (int rt = 0; rt < 5; ++rt)
#pragma unroll
        for (int e = 0; e < 4; ++e) c2[rt][e] = 0.f;

    const int m16 = lane & 15;
    const int kgr = lane >> 4;
#pragma unroll 2
    for (int ks2 = 0; ks2 < 8; ++ks2) {
        const half8 bf = *(const half8*)&hidf[FOFF((ks2 * 4 + w) * 64 + lane)];
#pragma unroll
        for (int rt = 0; rt < 5; ++rt) {
            const half8 af = *(const half8*)(w2s + ((size_t)(rt * 8 + ks2) * 64 + lane) * 8);
            c2[rt] = __builtin_amdgcn_mfma_f32_16x16x32_f16(af, bf, c2[rt], 0, 0, 0);
        }
    }
    __syncthreads();   // all hidf reads done; alias LDS as x2t/prop

    // ---- write x2 (global, for tail) + x2 tile (LDS, for IoU) ----
    float* xb = x2 + (size_t)b * OC * HW + p0 + w * 16 + m16;
    const int pxl = w * 16 + m16;
#pragma unroll
    for (int rt = 0; rt < 5; ++rt) {
#pragma unroll
        for (int r = 0; r < 4; ++r) {
            const int o2 = rt * 16 + kgr * 4 + r;
            const float v = c2[rt][r] + b2[o2];
            if (o2 < OC) {
                xb[(size_t)o2 * HW] = v;
                x2t[pxl * 69 + o2] = v;
            }
        }
    }
    __syncthreads();

    // ---- build 576 proposals (a, px) into LDS ----
    for (int pi = t; pi < A_ * 64; pi += 256) {
        const int a  = pi >> 6;
        const int px = pi & 63;
        const float* xr = x2t + px * 69 + 5 * a;
        const float tx = xr[1], ty = xr[2], tw = xr[3], th = xr[4];
        const int hw = p0 + px;
        const int h  = hw / W_;
        const int wv = hw - h * W_;
        const float gx = (float)wv + 0.5f;
        const float gy = (float)h + 0.5f;
        const float nw = anc[2 * a]     * __expf(tw);
        const float nh = anc[2 * a + 1] * __expf(th);
        const float cx = gx + tx, cy = gy + ty;
        ppx1[pi] = cx - 0.5f * nw; ppy1[pi] = cy - 0.5f * nh;
        ppx2[pi] = cx + 0.5f * nw; ppy2[pi] = cy + 0.5f * nh;
        pare[pi] = nw * nh;
    }
    __syncthreads();

    // ---- IoU stream-out: per (a,q) each wave stores one contiguous 1KB span ----
    const int pr = lane >> 4;
    const int j0 = (lane & 15) * 4;
    float Bx1[4], By1[4], Bx2[4], By2[4], Ba[4];
#pragma unroll
    for (int e = 0; e < 4; ++e) {
        Bx1[e] = boxs[j0 + e];       By1[e] = boxs[64 + j0 + e];
        Bx2[e] = boxs[128 + j0 + e]; By2[e] = boxs[192 + j0 + e];
        Ba[e]  = boxs[256 + j0 + e];
    }
    float* ibase = iou_out + ((size_t)b * AHW + p0) * 64;
#pragma unroll 1
    for (int a = 0; a < A_; ++a) {
#pragma unroll
        for (int q = 0; q < 4; ++q) {
            const int p = w * 16 + q * 4 + pr;
            const int i = a * 64 + p;
            const float Px1 = ppx1[i], Py1 = ppy1[i], Px2 = ppx2[i], Py2 = ppy2[i];
            const float pa = pare[i];
            f32x4 o4;
#pragma unroll
            for (int e = 0; e < 4; ++e) {
                const float iw = fminf(Px2, Bx2[e]) - fmaxf(Px1, Bx1[e]);
                const float ih = fminf(Py2, By2[e]) - fmaxf(Py1, By1[e]);
                const float inter = fmaxf(iw, 0.f) * fmaxf(ih, 0.f);
                o4[e] = inter * __builtin_amdgcn_rcpf(Ba[e] + pa - inter);
            }
            __builtin_nontemporal_store(o4, (f32x4*)(ibase + ((size_t)a * HW + p) * 64 + j0));
        }
    }
}

// blocks 0..39: class_pos gather (1024 thr); block 40: loss reduction.
__global__ __launch_bounds__(1024) void tail_kernel(
    const float* __restrict__ x2, const int* __restrict__ pos_idx,
    const int* __restrict__ neg_idx, const float* __restrict__ gt_off,
    float* __restrict__ cls_out, float* __restrict__ out0)
{
    const int t = threadIdx.x;
    if (blockIdx.x < 40) {
        const int g = blockIdx.x * 1024 + t;   // 0..40959
        const int m = g / CNUM;
        const int c = g - m * CNUM;
        const int idx = pos_idx[m];
        const int bi  = idx / AHW;
        const int hw  = idx % HW;
        cls_out[g] = x2[((size_t)bi * OC + 45 + c) * HW + hw];
        return;
    }
    float csum = 0.f, rsum = 0.f;
    for (int m = t; m < M_; m += 1024) {
        const int idx = pos_idx[m];
        const int bi = idx / AHW;
        const int rr = idx - bi * AHW;
        const int a  = rr / HW;
        const int hw = rr - a * HW;
        const float* xb = x2 + ((size_t)bi * OC + 5 * a) * HW + hw;
        const float s = 1.f / (1.f + __expf(-xb[0]));
        csum += (s - 1.f) * (s - 1.f);
#pragma unroll
        for (int k = 0; k < 4; ++k) {
            const float d = xb[(size_t)(k + 1) * HW] - gt_off[m * 4 + k];
            rsum += d * d;
        }
    }
    for (int m = t; m < M_; m += 1024) {
        const int idx = neg_idx[m];
        const int bi = idx / AHW;
        const int rr = idx - bi * AHW;
        const int a  = rr / HW;
        const int hw = rr - a * HW;
        const float s = 1.f / (1.f + __expf(-x2[((size_t)bi * OC + 5 * a) * HW + hw]));
        csum += s * s;
    }
    __shared__ float red[32];
#pragma unroll
    for (int off = 32; off > 0; off >>= 1) {
        csum += __shfl_down(csum, off, 64);
        rsum += __shfl_down(rsum, off, 64);
    }
    if ((t & 63) == 0) { red[t >> 6] = csum; red[16 + (t >> 6)] = rsum; }
    __syncthreads();
    if (t == 0) {
        float c = 0.f, rg = 0.f;
#pragma unroll
        for (int i = 0; i < 16; ++i) { c += red[i]; rg += red[16 + i]; }
        out0[0] = c / (2.f * (float)M_) + rg / (float)M_;
    }
}

extern "C" void kernel_launch(void* const* d_in, const int* in_sizes, int n_in,
                              void* d_out, int out_size, void* d_ws, size_t ws_size,
                              hipStream_t stream) {
    (void)in_sizes; (void)n_in; (void)out_size; (void)ws_size;
    const float* features = (const float*)d_in[0];
    const float* w1       = (const float*)d_in[1];
    const float* b1       = (const float*)d_in[2];
    const float* w2       = (const float*)d_in[3];
    const float* b2       = (const float*)d_in[4];
    const float* anc      = (const float*)d_in[5];
    const float* bboxes   = (const float*)d_in[7];
    const float* gt_off   = (const float*)d_in[8];
    const int*   pos_idx  = (const int*)d_in[9];
    const int*   neg_idx  = (const int*)d_in[10];
    float* out = (float*)d_out;

    char* wsb = (char*)d_ws;
    float* x2 = (float*)wsb;                                  // 26,091,520 B
    _Float16* w1s = (_Float16*)(wsb + X2_BYTES);              // 131,072 B
    _Float16* w2s = w1s + 65536;                              // 40,960 B

    prep_kernel<<<256, 256, 0, stream>>>(w1, w2, w1s, w2s);
    conv_iou_kernel<<<B_ * NTILE, 256, 0, stream>>>(features, w1s, b1, w2s, b2,
                                                    anc, bboxes, x2, out + 1);
    tail_kernel<<<41, 1024, 0, stream>>>(x2, pos_idx, neg_idx, gt_off, out + 1 + IOU_N, out);
}